// Round 14
// baseline (485.382 us; speedup 1.0000x reference)
//
#include <hip/hip_runtime.h>
#include <hip/hip_bf16.h>

// Problem constants
#define BB 8
#define NN 1024
#define DD 256
#define HH 8
#define DK 32
#define FFN 1024
#define NLAYERS 4
#define MM (BB * NN)          // 8192 rows
#define ROW_ELEMS (MM * DD)   // 2,097,152

// 1/sqrt(32) * log2(e)  (log2e folded so attention uses native exp2)
#define QSCALE 0.2550655192922103f
#define LOG2E  1.4426950408889634f

typedef unsigned short ushort_t;
typedef __attribute__((ext_vector_type(8))) short bf16x8;
typedef __attribute__((ext_vector_type(4))) short bf16x4;
typedef __attribute__((ext_vector_type(4))) float f32x4;

// K=16 bf16 MFMA: builtin if present on device; inline-asm fallback; host stub.
__device__ __forceinline__ f32x4 mfma16(bf16x4 a, bf16x4 b, f32x4 c) {
#if __has_builtin(__builtin_amdgcn_mfma_f32_16x16x16bf16_1k)
    return __builtin_amdgcn_mfma_f32_16x16x16bf16_1k(a, b, c, 0, 0, 0);
#elif defined(__AMDGCN__)
    f32x4 d;
    asm volatile("v_mfma_f32_16x16x16_bf16 %0, %1, %2, %3"
                 : "=v"(d)
                 : "v"(a), "v"(b), "v"(c));
    return d;
#else
    return c;  // host-pass stub
#endif
}

__device__ __forceinline__ ushort_t f2b(float f) {
    __hip_bfloat16 h = __float2bfloat16(f);
    return *reinterpret_cast<ushort_t*>(&h);
}

// async global -> LDS, 16 B per lane. LDS dest = wave-uniform base + lane*16B.
__device__ __forceinline__ void async_ld16(const void* g, void* l) {
    __builtin_amdgcn_global_load_lds((const __attribute__((address_space(1))) void*)g,
                                     (__attribute__((address_space(3))) void*)l, 16, 0, 0);
}

// ---------------------------------------------------------------------------
// copy-in: x -> xf (f32) + xb (bf16)
// ---------------------------------------------------------------------------
__global__ __launch_bounds__(256) void copy_in_kernel(const float* __restrict__ in,
                                                      float* __restrict__ xf,
                                                      ushort_t* __restrict__ xb, int n) {
    int i = blockIdx.x * 256 + threadIdx.x;
    if (i < n) { float v = in[i]; xf[i] = v; xb[i] = f2b(v); }
}

// ---------------------------------------------------------------------------
// Fused weight prep (one dispatch): 5 transposes + bias concat.
// ---------------------------------------------------------------------------
__global__ __launch_bounds__(256) void prep_kernel(const float* __restrict__ Wq,
                                                   const float* __restrict__ Wk,
                                                   const float* __restrict__ Wv,
                                                   const float* __restrict__ W1,
                                                   const float* __restrict__ W2,
                                                   const float* __restrict__ bq,
                                                   const float* __restrict__ bk,
                                                   const float* __restrict__ bv,
                                                   ushort_t* __restrict__ wqkvt,
                                                   ushort_t* __restrict__ w1t,
                                                   ushort_t* __restrict__ w2t,
                                                   float* __restrict__ bqkv) {
    const int id = blockIdx.x;
    const int layer = id / 707;
    const int r = id % 707;
    const int tid = threadIdx.x;

    if (r >= 704) {  // bias concat: 3 chunks of 256
        const int chunk = r - 704;
        const float* src = (chunk == 0) ? bq : (chunk == 1) ? bk : bv;
        bqkv[layer * 768 + chunk * 256 + tid] = src[layer * 256 + tid];
        return;
    }

    const float* src;
    ushort_t* dst;
    int R, C, x, y;
    if (r < 192) {
        const int w = r >> 6, rr = r & 63;
        src = ((w == 0) ? Wq : (w == 1) ? Wk : Wv) + (size_t)layer * 65536;
        dst = wqkvt + (size_t)layer * 196608 + w * 65536;
        R = 256; C = 256; x = rr & 7; y = rr >> 3;
    } else if (r < 448) {
        const int rr = r - 192;
        src = W1 + (size_t)layer * 262144;
        dst = w1t + (size_t)layer * 262144;
        R = 256; C = 1024; x = rr & 31; y = rr >> 5;
    } else {
        const int rr = r - 448;
        src = W2 + (size_t)layer * 262144;
        dst = w2t + (size_t)layer * 262144;
        R = 1024; C = 256; x = rr & 7; y = rr >> 3;
    }
    const int r0 = y * 32, c0 = x * 32;
    __shared__ float tile[32][33];
    const int tx = tid & 31, ty = tid >> 5;
#pragma unroll
    for (int i = 0; i < 4; ++i)
        tile[ty + 8 * i][tx] = src[(size_t)(r0 + ty + 8 * i) * C + (c0 + tx)];
    __syncthreads();
#pragma unroll
    for (int i = 0; i < 4; ++i)
        dst[(size_t)(c0 + ty + 8 * i) * R + (r0 + tx)] = f2b(tile[tx][ty + 8 * i]);
}

// ---------------------------------------------------------------------------
// MFMA bf16 GEMM, async global_load_lds staging (16B).
// MODE 0: f32 out. MODE 1: relu + bf16 out. MODE 2: QKV scatter epilogue into
// Qa[bh][n][64] (x QSCALE, + alpha*log2e*coords in dims 32..34),
// Ka[bh][n][64] (+ coords in dims 32..34), Vt[bh][d][n] (packed ushort4).
// ---------------------------------------------------------------------------
template <int MODE, int BM>
__global__ __launch_bounds__(256) void mfma_gemm_kernel(const ushort_t* __restrict__ A,
                                                        const ushort_t* __restrict__ Bt,
                                                        const float* __restrict__ bias,
                                                        void* __restrict__ C0,
                                                        void* __restrict__ C1,
                                                        void* __restrict__ C2,
                                                        const float* __restrict__ coords,
                                                        const float* __restrict__ alpha, int layer,
                                                        int K, int ldc) {
    constexpr int NI = BM / 32;
    __shared__ ushort_t As[BM * 32];
    __shared__ ushort_t Bs[128 * 32];

    const int t    = threadIdx.x;
    const int bm   = blockIdx.y * BM;
    const int bn   = blockIdx.x * 128;
    const int wave = t >> 6, lane = t & 63;
    const int wm   = (wave >> 1) * (BM / 2), wn = (wave & 1) * 64;
    const int quad = lane >> 4, l16 = lane & 15;

    const int srow = t >> 2;
    const int scol = (t & 3) * 8;

    f32x4 acc[NI][4];
#pragma unroll
    for (int i = 0; i < NI; ++i)
#pragma unroll
        for (int j = 0; j < 4; ++j) {
            f32x4 z = {0.f, 0.f, 0.f, 0.f};
            acc[i][j] = z;
        }

    for (int k0 = 0; k0 < K; k0 += 32) {
        __syncthreads();
        async_ld16(A + (size_t)(bm + srow) * K + k0 + scol, As + wave * 512);
        if constexpr (BM == 128)
            async_ld16(A + (size_t)(bm + 64 + srow) * K + k0 + scol, As + 2048 + wave * 512);
        async_ld16(Bt + (size_t)(bn + srow) * K + k0 + scol, Bs + wave * 512);
        async_ld16(Bt + (size_t)(bn + 64 + srow) * K + k0 + scol, Bs + 2048 + wave * 512);
        __syncthreads();

        bf16x8 af[NI], bfr[4];
#pragma unroll
        for (int i = 0; i < NI; ++i)
            af[i] = *(const bf16x8*)(As + (wm + i * 16 + l16) * 32 + quad * 8);
#pragma unroll
        for (int j = 0; j < 4; ++j)
            bfr[j] = *(const bf16x8*)(Bs + (wn + j * 16 + l16) * 32 + quad * 8);
#pragma unroll
        for (int i = 0; i < NI; ++i)
#pragma unroll
            for (int j = 0; j < 4; ++j)
                acc[i][j] = __builtin_amdgcn_mfma_f32_16x16x32_bf16(af[i], bfr[j], acc[i][j], 0, 0, 0);
    }

    const float av = (MODE == 2) ? alpha[layer] : 0.f;

#pragma unroll
    for (int j = 0; j < 4; ++j) {
        const int col = bn + wn + j * 16 + l16;
        const float bsv = bias[col];
#pragma unroll
        for (int i = 0; i < NI; ++i) {
            const int row0 = bm + wm + i * 16 + quad * 4;
            if (MODE == 2) {
                const int bb2 = row0 >> 10, nn0 = row0 & 1023;
                const int which = col >> 8, rem = col & 255;
                const int h = rem >> 5, d = rem & 31;
                const size_t bh = (size_t)((bb2 << 3) + h);
                if (which == 2) {
                    ushort4 pk;
                    pk.x = f2b(acc[i][j][0] + bsv);
                    pk.y = f2b(acc[i][j][1] + bsv);
                    pk.z = f2b(acc[i][j][2] + bsv);
                    pk.w = f2b(acc[i][j][3] + bsv);
                    *(ushort4*)&((ushort_t*)C2)[(bh * DK + d) * NN + nn0] = pk;
                } else {
#pragma unroll
                    for (int r = 0; r < 4; ++r) {
                        const float v = acc[i][j][r] + bsv;
                        const int nn = nn0 + r;
                        if (which == 0) {
                            ((ushort_t*)C0)[(bh * NN + nn) * 64 + d] = f2b(v * QSCALE);
                            ushort_t ext = 0;
                            if (d < 3) ext = f2b(av * LOG2E * coords[(size_t)(bb2 * NN + nn) * 3 + d]);
                            ((ushort_t*)C0)[(bh * NN + nn) * 64 + 32 + d] = ext;
                        } else {
                            ((ushort_t*)C1)[(bh * NN + nn) * 64 + d] = f2b(v);
                            ushort_t ext = 0;
                            if (d < 3) ext = f2b(coords[(size_t)(bb2 * NN + nn) * 3 + d]);
                            ((ushort_t*)C1)[(bh * NN + nn) * 64 + 32 + d] = ext;
                        }
                    }
                }
            } else {
#pragma unroll
                for (int r = 0; r < 4; ++r) {
                    float v = acc[i][j][r] + bsv;
                    if (MODE == 0)
                        ((float*)C0)[(size_t)(row0 + r) * ldc + col] = v;
                    else
                        ((ushort_t*)C0)[(size_t)(row0 + r) * ldc + col] = f2b(fmaxf(v, 0.f));
                }
            }
        }
    }
}

// ---------------------------------------------------------------------------
// MFMA flash attention v7 — attn8's zero-P-LDS design at 32-key tiles for
// occupancy: LDS 56 KB -> 29 KB, prefetch regs halved, __launch_bounds__
// (256,3) -> 3 blocks/CU (12 waves) vs 2. Same math/layout identities:
// S^T C-layout (row=key, col=q=l16) IS the K=16 MFMA B-operand layout; PV
// runs transposed in-register (no LDS P, no waitcnt/barriers in main loop).
// Wave w owns disjoint keys [w*256,+256); per-lane l + 2 shfl_xor. XCD
// swizzle: b=blockIdx.x,h=y -> same-(b,h) blocks stride 64 = 0 mod 8.
// ---------------------------------------------------------------------------
__global__ __launch_bounds__(256, 3) void attn9_kernel(const ushort_t* __restrict__ Qa,
                                                       const ushort_t* __restrict__ Ka,
                                                       const ushort_t* __restrict__ Vt,
                                                       float* __restrict__ aout) {
    const int b = blockIdx.x, h = blockIdx.y, n0 = blockIdx.z * 64;
    const int t = threadIdx.x, wave = t >> 6, lane = t & 63;
    const int quad = lane >> 4, l16 = lane & 15;
    const int bh = b * HH + h;

    __shared__ __align__(16) char smem[29696];
    ushort_t (*Ks)[32][72] = (ushort_t (*)[32][72])smem;             // [4] 18432 B
    ushort_t (*Vs)[32][40] = (ushort_t (*)[32][40])(smem + 18432);   // [4] 10240 B
    float    (*Om)[32][36] = (float (*)[32][36])smem;                // merge alias 18432 B
    float    (*Lm)[64]     = (float (*)[64])(smem + 28672);          // 1024 B

    // Q fragments: 4 subtiles of 16 q-rows (block's 64 q, held by every wave)
    bf16x8 aq[4][2];
#pragma unroll
    for (int s = 0; s < 4; ++s) {
        const ushort_t* qp = Qa + ((size_t)bh * NN + n0 + s * 16 + l16) * 64 + quad * 8;
        aq[s][0] = *(const bf16x8*)qp;
        aq[s][1] = *(const bf16x8*)(qp + 32);
    }

    const f32x4 z = {0.f, 0.f, 0.f, 0.f};
    f32x4 acc[4][2];
    float lsum[4];
#pragma unroll
    for (int s = 0; s < 4; ++s) { acc[s][0] = z; acc[s][1] = z; lsum[s] = 0.f; }

    const ushort_t* kg = Ka + ((size_t)bh * NN + wave * 256) * 64;
    const ushort_t* vg = Vt + (size_t)bh * DK * NN + wave * 256;

    // K staging: row = lane>>1 (0..31), 4 x 16B chunks at (lane&1)*32 + i*8
    const int krow = lane >> 1, kch = (lane & 1) * 32;
    // V staging: row d = lane>>1 (0..31), 2 x 16B chunks at (lane&1)*16 + i*8
    const int vrow = lane >> 1, vch = (lane & 1) * 16;

    uint4 kreg[4], vreg[2];
#pragma unroll
    for (int i = 0; i < 4; ++i) kreg[i] = *(const uint4*)(kg + (size_t)krow * 64 + kch + i * 8);
#pragma unroll
    for (int i = 0; i < 2; ++i) vreg[i] = *(const uint4*)(vg + (size_t)vrow * NN + vch + i * 8);

    for (int kt = 0; kt < 8; ++kt) {
        // write staged tile (compiler inserts lgkmcnt before first frag use)
#pragma unroll
        for (int i = 0; i < 4; ++i) *(uint4*)&Ks[wave][krow][kch + i * 8] = kreg[i];
#pragma unroll
        for (int i = 0; i < 2; ++i) *(uint4*)&Vs[wave][vrow][vch + i * 8] = vreg[i];

        bf16x8 bk0[2], bk1[2];
#pragma unroll
        for (int jt = 0; jt < 2; ++jt) {
            bk0[jt] = *(const bf16x8*)&Ks[wave][jt * 16 + l16][quad * 8];
            bk1[jt] = *(const bf16x8*)&Ks[wave][jt * 16 + l16][32 + quad * 8];
        }
        bf16x4 vfrag[2][2];
#pragma unroll
        for (int g = 0; g < 2; ++g)
#pragma unroll
            for (int jt = 0; jt < 2; ++jt)
                vfrag[g][jt] = *(const bf16x4*)&Vs[wave][g * 16 + l16][jt * 16 + quad * 4];

        // prefetch next tile's K/V into registers (hidden behind compute)
        if (kt < 7) {
            const ushort_t* kg2 = kg + (size_t)(kt + 1) * 32 * 64;
            const ushort_t* vg2 = vg + (kt + 1) * 32;
#pragma unroll
            for (int i = 0; i < 4; ++i)
                kreg[i] = *(const uint4*)(kg2 + (size_t)krow * 64 + kch + i * 8);
#pragma unroll
            for (int i = 0; i < 2; ++i)
                vreg[i] = *(const uint4*)(vg2 + (size_t)vrow * NN + vch + i * 8);
        }

#pragma unroll
        for (int s = 0; s < 4; ++s) {
            // S^T: D[key=jt*16+quad*4+r][q=l16]
            f32x4 st[2];
#pragma unroll
            for (int jt = 0; jt < 2; ++jt) {
                st[jt] = __builtin_amdgcn_mfma_f32_16x16x32_bf16(bk0[jt], aq[s][0], z, 0, 0, 0);
                st[jt] = __builtin_amdgcn_mfma_f32_16x16x32_bf16(bk1[jt], aq[s][1], st[jt], 0, 0, 0);
            }
            // exp2 + in-lane pack: B-operand of the K=16 MFMA (n=l16, k=quad*4+j)
            bf16x4 pf[2];
            float ls = 0.f;
#pragma unroll
            for (int jt = 0; jt < 2; ++jt) {
                float e0 = exp2f(st[jt][0]);
                float e1 = exp2f(st[jt][1]);
                float e2 = exp2f(st[jt][2]);
                float e3 = exp2f(st[jt][3]);
                ls += (e0 + e1) + (e2 + e3);
                pf[jt][0] = (short)f2b(e0);
                pf[jt][1] = (short)f2b(e1);
                pf[jt][2] = (short)f2b(e2);
                pf[jt][3] = (short)f2b(e3);
            }
            lsum[s] += ls;
            // O^T += V^T . P^T  (K=16 per MFMA)
#pragma unroll
            for (int jt = 0; jt < 2; ++jt) {
                acc[s][0] = mfma16(vfrag[0][jt], pf[jt], acc[s][0]);
                acc[s][1] = mfma16(vfrag[1][jt], pf[jt], acc[s][1]);
            }
        }
    }

    // reduce l across the 4 quads (same q, disjoint key%16 subsets)
#pragma unroll
    for (int s = 0; s < 4; ++s) {
        lsum[s] += __shfl_xor(lsum[s], 16);
        lsum[s] += __shfl_xor(lsum[s], 32);
    }

    __syncthreads();   // all waves done with Ks/Vs — safe to alias as Om/Lm
    if (quad == 0) {
#pragma unroll
        for (int s = 0; s < 4; ++s) Lm[wave][s * 16 + l16] = lsum[s];
    }

    // two merge phases of 32 q each (Om alias fits in the Ks region)
#pragma unroll
    for (int phase = 0; phase < 2; ++phase) {
#pragma unroll
        for (int si = 0; si < 2; ++si) {
            const int s = phase * 2 + si;
            const int q = si * 16 + l16;
#pragma unroll
            for (int g = 0; g < 2; ++g) {
                float4 v = {acc[s][g][0], acc[s][g][1], acc[s][g][2], acc[s][g][3]};
                *(float4*)&Om[wave][q][g * 16 + quad * 4] = v;
            }
        }
        __syncthreads();
        {
            const int q = t >> 3, dseg = (t & 7) * 4;    // 32 q x 8 segs x 4 d
            const int qq = phase * 32 + q;
            const float inv = 1.0f / (Lm[0][qq] + Lm[1][qq] + Lm[2][qq] + Lm[3][qq]);
            float* op = aout + (size_t)(b * NN + n0 + qq) * DD + h * DK + dseg;
            float4 s0 = {0.f, 0.f, 0.f, 0.f};
#pragma unroll
            for (int w = 0; w < 4; ++w) {
                float4 a = *(const float4*)&Om[w][q][dseg];
                s0.x += a.x; s0.y += a.y; s0.z += a.z; s0.w += a.w;
            }
            float4 o0 = {s0.x * inv, s0.y * inv, s0.z * inv, s0.w * inv};
            *(float4*)op = o0;
        }
        __syncthreads();   // before next phase overwrites Om
    }
}

// ---------------------------------------------------------------------------
// xout = LayerNorm(x + delta) * g + be ; also writes bf16 xb.
// ---------------------------------------------------------------------------
__global__ __launch_bounds__(256) void addln_kernel(const float* __restrict__ x,
                                                    ushort_t* __restrict__ xb,
                                                    const float* __restrict__ delta, int dstride,
                                                    const float* __restrict__ g,
                                                    const float* __restrict__ be,
                                                    float* __restrict__ xout) {
    const int row  = blockIdx.x * 4 + (threadIdx.x >> 6);
    const int lane = threadIdx.x & 63;
    const size_t base = (size_t)row * DD + lane * 4;

    float4 xv = *(const float4*)(x + base);
    float4 dl = *(const float4*)(delta + (size_t)row * dstride + lane * 4);
    float v0 = xv.x + dl.x, v1 = xv.y + dl.y, v2 = xv.z + dl.z, v3 = xv.w + dl.w;

    float s = v0 + v1 + v2 + v3;
#pragma unroll
    for (int off = 32; off; off >>= 1) s += __shfl_xor(s, off);
    const float mean = s * (1.0f / 256.0f);

    float d0 = v0 - mean, d1 = v1 - mean, d2 = v2 - mean, d3 = v3 - mean;
    float s2 = d0 * d0 + d1 * d1 + d2 * d2 + d3 * d3;
#pragma unroll
    for (int off = 32; off; off >>= 1) s2 += __shfl_xor(s2, off);
    const float rs = rsqrtf(s2 * (1.0f / 256.0f) + 1e-5f);

    float4 gv = *(const float4*)(g + lane * 4);
    float4 bv = *(const float4*)(be + lane * 4);
    float y0 = d0 * rs * gv.x + bv.x;
    float y1 = d1 * rs * gv.y + bv.y;
    float y2 = d2 * rs * gv.z + bv.z;
    float y3 = d3 * rs * gv.w + bv.w;

    float4 o = {y0, y1, y2, y3};
    *(float4*)(xout + base) = o;
    ushort4 ob = {f2b(y0), f2b(y1), f2b(y2), f2b(y3)};
    *(ushort4*)(xb + base) = ob;
}

// ---------------------------------------------------------------------------
// launch — workspace ~45.5 MB
// ---------------------------------------------------------------------------
extern "C" void kernel_launch(void* const* d_in, const int* in_sizes, int n_in,
                              void* d_out, int out_size, void* d_ws, size_t ws_size,
                              hipStream_t stream) {
    const float* x      = (const float*)d_in[0];
    const float* coords = (const float*)d_in[1];
    const float* Wq     = (const float*)d_in[2];
    const float* bq     = (const float*)d_in[3];
    const float* Wk     = (const float*)d_in[4];
    const float* bk     = (const float*)d_in[5];
    const float* Wv     = (const float*)d_in[6];
    const float* bv     = (const float*)d_in[7];
    const float* alpha  = (const float*)d_in[8];
    const float* W1     = (const float*)d_in[9];
    const float* b1     = (const float*)d_in[10];
    const float* W2     = (const float*)d_in[11];
    const float* b2     = (const float*)d_in[12];
    const float* g1     = (const float*)d_in[13];
    const float* be1    = (const float*)d_in[14];
    const float* g2     = (const float*)d_in[15];
    const float* be2    = (const float*)d_in[16];

    float* ws = (float*)d_ws;
    float*    xf    = ws;                             // 8 MB
    ushort_t* xb    = (ushort_t*)(ws + 2097152);      // 4 MB
    ushort_t* Qa    = (ushort_t*)(ws + 3145728);      // 8 MB [64 bh][1024][64]
    ushort_t* Ka    = (ushort_t*)(ws + 5242880);      // 8 MB
    ushort_t* Vt    = (ushort_t*)(ws + 7340032);      // 4 MB [64 bh][32][1024]
    float*    aout  = ws + 8388608;                   // 8 MB [8192][256]
    ushort_t* wqkvt = (ushort_t*)(ws + 10485760);     // 1.5 MB  [L][768][256]
    ushort_t* w1t   = (ushort_t*)(ws + 10878976);     // 2 MB    [L][1024][256]
    ushort_t* w2t   = (ushort_t*)(ws + 11403264);     // 2 MB    [L][256][1024]
    float*    bqkv  = ws + 11927552;                  // [L][768]

    ushort_t* hidden = Qa;      // [8192][1024] bf16 = 16 MB, spans Qa+Ka (dead in FFN phase)
    float*    ff2out = aout;    // aout dead after addln1

    // ---- fused weight prep (one dispatch) ----
    prep_kernel<<<NLAYERS * 707, 256, 0, stream>>>(Wq, Wk, Wv, W1, W2, bq, bk, bv,
                                                   wqkvt, w1t, w2t, bqkv);

    copy_in_kernel<<<ROW_ELEMS / 256, 256, 0, stream>>>(x, xf, xb, ROW_ELEMS);

    for (int i = 0; i < NLAYERS; ++i) {
        // fused QKV GEMM (64-row tiles) with scatter epilogue (+ coord dims) -> Qa, Ka, Vt
        mfma_gemm_kernel<2, 64><<<dim3(6, 128), 256, 0, stream>>>(
            xb, wqkvt + (size_t)i * 196608, bqkv + i * 768, Qa, Ka, Vt,
            coords, alpha, i, 256, 0);

        attn9_kernel<<<dim3(8, 8, 16), 256, 0, stream>>>(Qa, Ka, Vt, aout);

        addln_kernel<<<MM / 4, 256, 0, stream>>>(xf, xb, aout, 256, g1 + i * 256, be1 + i * 256, xf);

        // FF1: [8192,256]@[256,1024] + relu -> hidden bf16
        mfma_gemm_kernel<1, 128><<<dim3(8, 64), 256, 0, stream>>>(
            xb, w1t + (size_t)i * 262144, b1 + i * 1024, hidden, nullptr, nullptr,
            nullptr, nullptr, 0, 256, 1024);
        // FF2: [8192,1024]@[1024,256] -> ff2out f32 (64-row tiles for 256-block grid)
        mfma_gemm_kernel<0, 64><<<dim3(2, 128), 256, 0, stream>>>(
            hidden, w2t + (size_t)i * 262144, b2 + i * 256, ff2out, nullptr, nullptr,
            nullptr, nullptr, 0, 1024, 256);

        addln_kernel<<<MM / 4, 256, 0, stream>>>(xf, xb, ff2out, 256, g2 + i * 256, be2 + i * 256,
                                                 (i == NLAYERS - 1) ? (float*)d_out : xf);
    }
}

// Round 15
// 453.461 us; speedup vs baseline: 1.0704x; 1.0704x over previous
//
#include <hip/hip_runtime.h>
#include <hip/hip_bf16.h>

// Problem constants
#define BB 8
#define NN 1024
#define DD 256
#define HH 8
#define DK 32
#define FFN 1024
#define NLAYERS 4
#define MM (BB * NN)          // 8192 rows
#define ROW_ELEMS (MM * DD)   // 2,097,152

// 1/sqrt(32) * log2(e)  (log2e folded so attention uses native exp2)
#define QSCALE 0.2550655192922103f
#define LOG2E  1.4426950408889634f

typedef unsigned short ushort_t;
typedef __attribute__((ext_vector_type(8))) short bf16x8;
typedef __attribute__((ext_vector_type(4))) short bf16x4;
typedef __attribute__((ext_vector_type(4))) float f32x4;

// K=16 bf16 MFMA: builtin if present on device; inline-asm fallback; host stub.
__device__ __forceinline__ f32x4 mfma16(bf16x4 a, bf16x4 b, f32x4 c) {
#if __has_builtin(__builtin_amdgcn_mfma_f32_16x16x16bf16_1k)
    return __builtin_amdgcn_mfma_f32_16x16x16bf16_1k(a, b, c, 0, 0, 0);
#elif defined(__AMDGCN__)
    f32x4 d;
    asm volatile("v_mfma_f32_16x16x16_bf16 %0, %1, %2, %3"
                 : "=v"(d)
                 : "v"(a), "v"(b), "v"(c));
    return d;
#else
    return c;  // host-pass stub
#endif
}

__device__ __forceinline__ ushort_t f2b(float f) {
    __hip_bfloat16 h = __float2bfloat16(f);
    return *reinterpret_cast<ushort_t*>(&h);
}

// async global -> LDS, 16 B per lane. LDS dest = wave-uniform base + lane*16B.
__device__ __forceinline__ void async_ld16(const void* g, void* l) {
    __builtin_amdgcn_global_load_lds((const __attribute__((address_space(1))) void*)g,
                                     (__attribute__((address_space(3))) void*)l, 16, 0, 0);
}

// ---------------------------------------------------------------------------
// copy-in: x -> xf (f32) + xb (bf16)
// ---------------------------------------------------------------------------
__global__ __launch_bounds__(256) void copy_in_kernel(const float* __restrict__ in,
                                                      float* __restrict__ xf,
                                                      ushort_t* __restrict__ xb, int n) {
    int i = blockIdx.x * 256 + threadIdx.x;
    if (i < n) { float v = in[i]; xf[i] = v; xb[i] = f2b(v); }
}

// ---------------------------------------------------------------------------
// Fused weight prep (one dispatch): 5 transposes + bias concat.
// ---------------------------------------------------------------------------
__global__ __launch_bounds__(256) void prep_kernel(const float* __restrict__ Wq,
                                                   const float* __restrict__ Wk,
                                                   const float* __restrict__ Wv,
                                                   const float* __restrict__ W1,
                                                   const float* __restrict__ W2,
                                                   const float* __restrict__ bq,
                                                   const float* __restrict__ bk,
                                                   const float* __restrict__ bv,
                                                   ushort_t* __restrict__ wqkvt,
                                                   ushort_t* __restrict__ w1t,
                                                   ushort_t* __restrict__ w2t,
                                                   float* __restrict__ bqkv) {
    const int id = blockIdx.x;
    const int layer = id / 707;
    const int r = id % 707;
    const int tid = threadIdx.x;

    if (r >= 704) {  // bias concat: 3 chunks of 256
        const int chunk = r - 704;
        const float* src = (chunk == 0) ? bq : (chunk == 1) ? bk : bv;
        bqkv[layer * 768 + chunk * 256 + tid] = src[layer * 256 + tid];
        return;
    }

    const float* src;
    ushort_t* dst;
    int R, C, x, y;
    if (r < 192) {
        const int w = r >> 6, rr = r & 63;
        src = ((w == 0) ? Wq : (w == 1) ? Wk : Wv) + (size_t)layer * 65536;
        dst = wqkvt + (size_t)layer * 196608 + w * 65536;
        R = 256; C = 256; x = rr & 7; y = rr >> 3;
    } else if (r < 448) {
        const int rr = r - 192;
        src = W1 + (size_t)layer * 262144;
        dst = w1t + (size_t)layer * 262144;
        R = 256; C = 1024; x = rr & 31; y = rr >> 5;
    } else {
        const int rr = r - 448;
        src = W2 + (size_t)layer * 262144;
        dst = w2t + (size_t)layer * 262144;
        R = 1024; C = 256; x = rr & 7; y = rr >> 3;
    }
    const int r0 = y * 32, c0 = x * 32;
    __shared__ float tile[32][33];
    const int tx = tid & 31, ty = tid >> 5;
#pragma unroll
    for (int i = 0; i < 4; ++i)
        tile[ty + 8 * i][tx] = src[(size_t)(r0 + ty + 8 * i) * C + (c0 + tx)];
    __syncthreads();
#pragma unroll
    for (int i = 0; i < 4; ++i)
        dst[(size_t)(c0 + ty + 8 * i) * R + (r0 + tx)] = f2b(tile[tx][ty + 8 * i]);
}

// ---------------------------------------------------------------------------
// MFMA bf16 GEMM, async global_load_lds staging (16B), BK=64 with SPLIT-HALF
// LDS buffers: each 32-wide K-half gets its own [rows][32] buffer (the proven
// bank-conflict-free fragment layout; padding is impossible with
// global_load_lds lane-contiguity). Same loads as BK=32, HALF the barrier
// drains. MODE 0: f32 out. MODE 1: relu + bf16 out. MODE 2: QKV scatter into
// Qa[bh][n][64] (x QSCALE, + alpha*log2e*coords in dims 32..34),
// Ka[bh][n][64] (+ coords), Vt[bh][d][n] (packed ushort4).
// ---------------------------------------------------------------------------
template <int MODE, int BM>
__global__ __launch_bounds__(256) void mfma_gemm_kernel(const ushort_t* __restrict__ A,
                                                        const ushort_t* __restrict__ Bt,
                                                        const float* __restrict__ bias,
                                                        void* __restrict__ C0,
                                                        void* __restrict__ C1,
                                                        void* __restrict__ C2,
                                                        const float* __restrict__ coords,
                                                        const float* __restrict__ alpha, int layer,
                                                        int K, int ldc) {
    constexpr int NI = BM / 32;
    __shared__ ushort_t As0[BM * 32];
    __shared__ ushort_t As1[BM * 32];
    __shared__ ushort_t Bs0[128 * 32];
    __shared__ ushort_t Bs1[128 * 32];

    const int t    = threadIdx.x;
    const int bm   = blockIdx.y * BM;
    const int bn   = blockIdx.x * 128;
    const int wave = t >> 6, lane = t & 63;
    const int wm   = (wave >> 1) * (BM / 2), wn = (wave & 1) * 64;
    const int quad = lane >> 4, l16 = lane & 15;

    const int srow = t >> 2;          // 0..63
    const int scol = (t & 3) * 8;     // 16B chunk within a 32-ushort half-row

    f32x4 acc[NI][4];
#pragma unroll
    for (int i = 0; i < NI; ++i)
#pragma unroll
        for (int j = 0; j < 4; ++j) {
            f32x4 z = {0.f, 0.f, 0.f, 0.f};
            acc[i][j] = z;
        }

    for (int k0 = 0; k0 < K; k0 += 64) {
        __syncthreads();
        // half 0 (k0 .. k0+31)
        async_ld16(A + (size_t)(bm + srow) * K + k0 + scol, As0 + wave * 512);
        if constexpr (BM == 128)
            async_ld16(A + (size_t)(bm + 64 + srow) * K + k0 + scol, As0 + 2048 + wave * 512);
        async_ld16(Bt + (size_t)(bn + srow) * K + k0 + scol, Bs0 + wave * 512);
        async_ld16(Bt + (size_t)(bn + 64 + srow) * K + k0 + scol, Bs0 + 2048 + wave * 512);
        // half 1 (k0+32 .. k0+63)
        async_ld16(A + (size_t)(bm + srow) * K + k0 + 32 + scol, As1 + wave * 512);
        if constexpr (BM == 128)
            async_ld16(A + (size_t)(bm + 64 + srow) * K + k0 + 32 + scol, As1 + 2048 + wave * 512);
        async_ld16(Bt + (size_t)(bn + srow) * K + k0 + 32 + scol, Bs1 + wave * 512);
        async_ld16(Bt + (size_t)(bn + 64 + srow) * K + k0 + 32 + scol, Bs1 + 2048 + wave * 512);
        __syncthreads();   // compiler drains vmcnt(0) -> LDS valid

        bf16x8 af0[NI], af1[NI], bf0[4], bf1[4];
#pragma unroll
        for (int i = 0; i < NI; ++i) {
            af0[i] = *(const bf16x8*)(As0 + (wm + i * 16 + l16) * 32 + quad * 8);
            af1[i] = *(const bf16x8*)(As1 + (wm + i * 16 + l16) * 32 + quad * 8);
        }
#pragma unroll
        for (int j = 0; j < 4; ++j) {
            bf0[j] = *(const bf16x8*)(Bs0 + (wn + j * 16 + l16) * 32 + quad * 8);
            bf1[j] = *(const bf16x8*)(Bs1 + (wn + j * 16 + l16) * 32 + quad * 8);
        }
#pragma unroll
        for (int i = 0; i < NI; ++i)
#pragma unroll
            for (int j = 0; j < 4; ++j) {
                acc[i][j] = __builtin_amdgcn_mfma_f32_16x16x32_bf16(af0[i], bf0[j], acc[i][j], 0, 0, 0);
                acc[i][j] = __builtin_amdgcn_mfma_f32_16x16x32_bf16(af1[i], bf1[j], acc[i][j], 0, 0, 0);
            }
    }

    const float av = (MODE == 2) ? alpha[layer] : 0.f;

#pragma unroll
    for (int j = 0; j < 4; ++j) {
        const int col = bn + wn + j * 16 + l16;
        const float bsv = bias[col];
#pragma unroll
        for (int i = 0; i < NI; ++i) {
            const int row0 = bm + wm + i * 16 + quad * 4;
            if (MODE == 2) {
                const int bb2 = row0 >> 10, nn0 = row0 & 1023;
                const int which = col >> 8, rem = col & 255;
                const int h = rem >> 5, d = rem & 31;
                const size_t bh = (size_t)((bb2 << 3) + h);
                if (which == 2) {
                    ushort4 pk;
                    pk.x = f2b(acc[i][j][0] + bsv);
                    pk.y = f2b(acc[i][j][1] + bsv);
                    pk.z = f2b(acc[i][j][2] + bsv);
                    pk.w = f2b(acc[i][j][3] + bsv);
                    *(ushort4*)&((ushort_t*)C2)[(bh * DK + d) * NN + nn0] = pk;
                } else {
#pragma unroll
                    for (int r = 0; r < 4; ++r) {
                        const float v = acc[i][j][r] + bsv;
                        const int nn = nn0 + r;
                        if (which == 0) {
                            ((ushort_t*)C0)[(bh * NN + nn) * 64 + d] = f2b(v * QSCALE);
                            ushort_t ext = 0;
                            if (d < 3) ext = f2b(av * LOG2E * coords[(size_t)(bb2 * NN + nn) * 3 + d]);
                            ((ushort_t*)C0)[(bh * NN + nn) * 64 + 32 + d] = ext;
                        } else {
                            ((ushort_t*)C1)[(bh * NN + nn) * 64 + d] = f2b(v);
                            ushort_t ext = 0;
                            if (d < 3) ext = f2b(coords[(size_t)(bb2 * NN + nn) * 3 + d]);
                            ((ushort_t*)C1)[(bh * NN + nn) * 64 + 32 + d] = ext;
                        }
                    }
                }
            } else {
#pragma unroll
                for (int r = 0; r < 4; ++r) {
                    float v = acc[i][j][r] + bsv;
                    if (MODE == 0)
                        ((float*)C0)[(size_t)(row0 + r) * ldc + col] = v;
                    else
                        ((ushort_t*)C0)[(size_t)(row0 + r) * ldc + col] = f2b(fmaxf(v, 0.f));
                }
            }
        }
    }
}

// ---------------------------------------------------------------------------
// MFMA flash attention (attn8, r13-verified config — 64-key tiles, LB(256,2)).
// 64 q-rows per block (4 subtiles), grid (8,8,16) with b=x,h=y (same-(b,h)
// blocks have id stride 64 = 0 mod 8 XCDs -> shared L2). Wave w owns disjoint
// keys [w*256,+256); no-max softmax partials combine exactly (validated r4+).
// S^T C-layout (row=key, col=q=l16) IS the K=16 MFMA's B-operand layout ->
// PV runs transposed with in-register exp2'd P; no LDS, no waitcnt, no
// barriers in the main loop. Per-lane l + 2 shfl_xor. K/V register prefetch.
// ---------------------------------------------------------------------------
__global__ __launch_bounds__(256, 2) void attn8_kernel(const ushort_t* __restrict__ Qa,
                                                       const ushort_t* __restrict__ Ka,
                                                       const ushort_t* __restrict__ Vt,
                                                       float* __restrict__ aout) {
    const int b = blockIdx.x, h = blockIdx.y, n0 = blockIdx.z * 64;
    const int t = threadIdx.x, wave = t >> 6, lane = t & 63;
    const int quad = lane >> 4, l16 = lane & 15;
    const int bh = b * HH + h;

    __shared__ __align__(16) char smem[56320];
    ushort_t (*Ks)[64][72] = (ushort_t (*)[64][72])smem;             // [4] 36864 B
    ushort_t (*Vs)[32][72] = (ushort_t (*)[32][72])(smem + 36864);   // [4] 18432 B
    float    (*Om)[64][36] = (float (*)[64][36])smem;                // merge alias (36864 B)
    float    (*Lm)[64]     = (float (*)[64])(smem + 55296);          // 1024 B

    // Q fragments: 4 subtiles of 16 q-rows (block's 64 q, held by every wave)
    bf16x8 aq[4][2];
#pragma unroll
    for (int s = 0; s < 4; ++s) {
        const ushort_t* qp = Qa + ((size_t)bh * NN + n0 + s * 16 + l16) * 64 + quad * 8;
        aq[s][0] = *(const bf16x8*)qp;
        aq[s][1] = *(const bf16x8*)(qp + 32);
    }

    const f32x4 z = {0.f, 0.f, 0.f, 0.f};
    f32x4 acc[4][2];
    float lsum[4];
#pragma unroll
    for (int s = 0; s < 4; ++s) { acc[s][0] = z; acc[s][1] = z; lsum[s] = 0.f; }

    const ushort_t* kg = Ka + ((size_t)bh * NN + wave * 256) * 64;
    const ushort_t* vg = Vt + (size_t)bh * DK * NN + wave * 256;

    const int srow = lane >> 3, sch = (lane & 7) * 8;   // staging: 8 rows x 8 chunks

    uint4 kreg[8], vreg[4];
#pragma unroll
    for (int i = 0; i < 8; ++i) kreg[i] = *(const uint4*)(kg + (size_t)(i * 8 + srow) * 64 + sch);
#pragma unroll
    for (int i = 0; i < 4; ++i) vreg[i] = *(const uint4*)(vg + (size_t)(i * 8 + srow) * NN + sch);

    for (int kt = 0; kt < 4; ++kt) {
        // write staged tile (same-wave LDS RAW is in-order: no barrier needed)
#pragma unroll
        for (int i = 0; i < 8; ++i) *(uint4*)&Ks[wave][i * 8 + srow][sch] = kreg[i];
#pragma unroll
        for (int i = 0; i < 4; ++i) *(uint4*)&Vs[wave][i * 8 + srow][sch] = vreg[i];

        // fragment reads (compiler inserts lgkmcnt before first use)
        bf16x8 bk0[4], bk1[4];
#pragma unroll
        for (int jt = 0; jt < 4; ++jt) {
            bk0[jt] = *(const bf16x8*)&Ks[wave][jt * 16 + l16][quad * 8];
            bk1[jt] = *(const bf16x8*)&Ks[wave][jt * 16 + l16][32 + quad * 8];
        }
        bf16x4 vfrag[2][4];
#pragma unroll
        for (int g = 0; g < 2; ++g)
#pragma unroll
            for (int jt = 0; jt < 4; ++jt)
                vfrag[g][jt] = *(const bf16x4*)&Vs[wave][g * 16 + l16][jt * 16 + quad * 4];

        // prefetch next tile's K/V into registers (hidden behind compute)
        if (kt < 3) {
            const ushort_t* kg2 = kg + (size_t)(kt + 1) * 64 * 64;
            const ushort_t* vg2 = vg + (kt + 1) * 64;
#pragma unroll
            for (int i = 0; i < 8; ++i)
                kreg[i] = *(const uint4*)(kg2 + (size_t)(i * 8 + srow) * 64 + sch);
#pragma unroll
            for (int i = 0; i < 4; ++i)
                vreg[i] = *(const uint4*)(vg2 + (size_t)(i * 8 + srow) * NN + sch);
        }

#pragma unroll
        for (int s = 0; s < 4; ++s) {
            // S^T: D[key=quad*4+r (+jt*16)][q=l16]
            f32x4 st[4];
#pragma unroll
            for (int jt = 0; jt < 4; ++jt) {
                st[jt] = __builtin_amdgcn_mfma_f32_16x16x32_bf16(bk0[jt], aq[s][0], z, 0, 0, 0);
                st[jt] = __builtin_amdgcn_mfma_f32_16x16x32_bf16(bk1[jt], aq[s][1], st[jt], 0, 0, 0);
            }
            // exp2 + in-lane pack: B-operand of the K=16 MFMA (n=l16, k=quad*4+j)
            bf16x4 pf[4];
            float ls = 0.f;
#pragma unroll
            for (int jt = 0; jt < 4; ++jt) {
                float e0 = exp2f(st[jt][0]);
                float e1 = exp2f(st[jt][1]);
                float e2 = exp2f(st[jt][2]);
                float e3 = exp2f(st[jt][3]);
                ls += (e0 + e1) + (e2 + e3);
                pf[jt][0] = (short)f2b(e0);
                pf[jt][1] = (short)f2b(e1);
                pf[jt][2] = (short)f2b(e2);
                pf[jt][3] = (short)f2b(e3);
            }
            lsum[s] += ls;
            // O^T += V^T . P^T  (K=16 per MFMA)
#pragma unroll
            for (int jt = 0; jt < 4; ++jt) {
                acc[s][0] = mfma16(vfrag[0][jt], pf[jt], acc[s][0]);
                acc[s][1] = mfma16(vfrag[1][jt], pf[jt], acc[s][1]);
            }
        }
    }

    // reduce l across the 4 quads (same q, disjoint key%16 subsets)
#pragma unroll
    for (int s = 0; s < 4; ++s) {
        lsum[s] += __shfl_xor(lsum[s], 16);
        lsum[s] += __shfl_xor(lsum[s], 32);
    }

    __syncthreads();   // all waves done with Ks/Vs — safe to alias as Om/Lm
    if (quad == 0) {
#pragma unroll
        for (int s = 0; s < 4; ++s) Lm[wave][s * 16 + l16] = lsum[s];
    }

    // write O^T partials: Om[wave][q][d]
#pragma unroll
    for (int s = 0; s < 4; ++s) {
        const int q = s * 16 + l16;
#pragma unroll
        for (int g = 0; g < 2; ++g) {
            float4 v = {acc[s][g][0], acc[s][g][1], acc[s][g][2], acc[s][g][3]};
            *(float4*)&Om[wave][q][g * 16 + quad * 4] = v;
        }
    }
    __syncthreads();

    {
        const int q = t >> 2, dseg = (t & 3) * 8;
        const float inv = 1.0f / (Lm[0][q] + Lm[1][q] + Lm[2][q] + Lm[3][q]);
        float* op = aout + (size_t)(b * NN + n0 + q) * DD + h * DK + dseg;
        float4 s0 = {0.f, 0.f, 0.f, 0.f}, s1 = {0.f, 0.f, 0.f, 0.f};
#pragma unroll
        for (int w = 0; w < 4; ++w) {
            float4 a = *(const float4*)&Om[w][q][dseg];
            float4 c = *(const float4*)&Om[w][q][dseg + 4];
            s0.x += a.x; s0.y += a.y; s0.z += a.z; s0.w += a.w;
            s1.x += c.x; s1.y += c.y; s1.z += c.z; s1.w += c.w;
        }
        float4 o0 = {s0.x * inv, s0.y * inv, s0.z * inv, s0.w * inv};
        float4 o1 = {s1.x * inv, s1.y * inv, s1.z * inv, s1.w * inv};
        *(float4*)op = o0;
        *(float4*)(op + 4) = o1;
    }
}

// ---------------------------------------------------------------------------
// xout = LayerNorm(x + delta) * g + be ; also writes bf16 xb.
// ---------------------------------------------------------------------------
__global__ __launch_bounds__(256) void addln_kernel(const float* __restrict__ x,
                                                    ushort_t* __restrict__ xb,
                                                    const float* __restrict__ delta, int dstride,
                                                    const float* __restrict__ g,
                                                    const float* __restrict__ be,
                                                    float* __restrict__ xout) {
    const int row  = blockIdx.x * 4 + (threadIdx.x >> 6);
    const int lane = threadIdx.x & 63;
    const size_t base = (size_t)row * DD + lane * 4;

    float4 xv = *(const float4*)(x + base);
    float4 dl = *(const float4*)(delta + (size_t)row * dstride + lane * 4);
    float v0 = xv.x + dl.x, v1 = xv.y + dl.y, v2 = xv.z + dl.z, v3 = xv.w + dl.w;

    float s = v0 + v1 + v2 + v3;
#pragma unroll
    for (int off = 32; off; off >>= 1) s += __shfl_xor(s, off);
    const float mean = s * (1.0f / 256.0f);

    float d0 = v0 - mean, d1 = v1 - mean, d2 = v2 - mean, d3 = v3 - mean;
    float s2 = d0 * d0 + d1 * d1 + d2 * d2 + d3 * d3;
#pragma unroll
    for (int off = 32; off; off >>= 1) s2 += __shfl_xor(s2, off);
    const float rs = rsqrtf(s2 * (1.0f / 256.0f) + 1e-5f);

    float4 gv = *(const float4*)(g + lane * 4);
    float4 bv = *(const float4*)(be + lane * 4);
    float y0 = d0 * rs * gv.x + bv.x;
    float y1 = d1 * rs * gv.y + bv.y;
    float y2 = d2 * rs * gv.z + bv.z;
    float y3 = d3 * rs * gv.w + bv.w;

    float4 o = {y0, y1, y2, y3};
    *(float4*)(xout + base) = o;
    ushort4 ob = {f2b(y0), f2b(y1), f2b(y2), f2b(y3)};
    *(ushort4*)(xb + base) = ob;
}

// ---------------------------------------------------------------------------
// launch — workspace ~45.5 MB
// ---------------------------------------------------------------------------
extern "C" void kernel_launch(void* const* d_in, const int* in_sizes, int n_in,
                              void* d_out, int out_size, void* d_ws, size_t ws_size,
                              hipStream_t stream) {
    const float* x      = (const float*)d_in[0];
    const float* coords = (const float*)d_in[1];
    const float* Wq     = (const float*)d_in[2];
    const float* bq     = (const float*)d_in[3];
    const float* Wk     = (const float*)d_in[4];
    const float* bk     = (const float*)d_in[5];
    const float* Wv     = (const float*)d_in[6];
    const float* bv     = (const float*)d_in[7];
    const float* alpha  = (const float*)d_in[8];
    const float* W1     = (const float*)d_in[9];
    const float* b1     = (const float*)d_in[10];
    const float* W2     = (const float*)d_in[11];
    const float* b2     = (const float*)d_in[12];
    const float* g1     = (const float*)d_in[13];
    const float* be1    = (const float*)d_in[14];
    const float* g2     = (const float*)d_in[15];
    const float* be2    = (const float*)d_in[16];

    float* ws = (float*)d_ws;
    float*    xf    = ws;                             // 8 MB
    ushort_t* xb    = (ushort_t*)(ws + 2097152);      // 4 MB
    ushort_t* Qa    = (ushort_t*)(ws + 3145728);      // 8 MB [64 bh][1024][64]
    ushort_t* Ka    = (ushort_t*)(ws + 5242880);      // 8 MB
    ushort_t* Vt    = (ushort_t*)(ws + 7340032);      // 4 MB [64 bh][32][1024]
    float*    aout  = ws + 8388608;                   // 8 MB [8192][256]
    ushort_t* wqkvt = (ushort_t*)(ws + 10485760);     // 1.5 MB  [L][768][256]
    ushort_t* w1t   = (ushort_t*)(ws + 10878976);     // 2 MB    [L][1024][256]
    ushort_t* w2t   = (ushort_t*)(ws + 11403264);     // 2 MB    [L][256][1024]
    float*    bqkv  = ws + 11927552;                  // [L][768]

    ushort_t* hidden = Qa;      // [8192][1024] bf16 = 16 MB, spans Qa+Ka (dead in FFN phase)
    float*    ff2out = aout;    // aout dead after addln1

    // ---- fused weight prep (one dispatch) ----
    prep_kernel<<<NLAYERS * 707, 256, 0, stream>>>(Wq, Wk, Wv, W1, W2, bq, bk, bv,
                                                   wqkvt, w1t, w2t, bqkv);

    copy_in_kernel<<<ROW_ELEMS / 256, 256, 0, stream>>>(x, xf, xb, ROW_ELEMS);

    for (int i = 0; i < NLAYERS; ++i) {
        // fused QKV GEMM (64-row tiles) with scatter epilogue (+ coord dims) -> Qa, Ka, Vt
        mfma_gemm_kernel<2, 64><<<dim3(6, 128), 256, 0, stream>>>(
            xb, wqkvt + (size_t)i * 196608, bqkv + i * 768, Qa, Ka, Vt,
            coords, alpha, i, 256, 0);

        attn8_kernel<<<dim3(8, 8, 16), 256, 0, stream>>>(Qa, Ka, Vt, aout);

        addln_kernel<<<MM / 4, 256, 0, stream>>>(xf, xb, aout, 256, g1 + i * 256, be1 + i * 256, xf);

        // FF1: [8192,256]@[256,1024] + relu -> hidden bf16
        mfma_gemm_kernel<1, 128><<<dim3(8, 64), 256, 0, stream>>>(
            xb, w1t + (size_t)i * 262144, b1 + i * 1024, hidden, nullptr, nullptr,
            nullptr, nullptr, 0, 256, 1024);
        // FF2: [8192,1024]@[1024,256] -> ff2out f32 (64-row tiles for 256-block grid)
        mfma_gemm_kernel<0, 64><<<dim3(2, 128), 256, 0, stream>>>(
            hidden, w2t + (size_t)i * 262144, b2 + i * 256, ff2out, nullptr, nullptr,
            nullptr, nullptr, 0, 1024, 256);

        addln_kernel<<<MM / 4, 256, 0, stream>>>(xf, xb, ff2out, 256, g2 + i * 256, be2 + i * 256,
                                                 (i == NLAYERS - 1) ? (float*)d_out : xf);
    }
}